// Round 11
// baseline (353.211 us; speedup 1.0000x reference)
//
#include <hip/hip_runtime.h>
#include <hip/hip_fp16.h>
#include <stdint.h>

typedef _Float16 half_t;
typedef __attribute__((ext_vector_type(8))) _Float16 half8;   // MFMA A/B frag (4 VGPRs)
typedef __attribute__((ext_vector_type(16))) float f32x16;    // 32x32 MFMA C/D frag
typedef __attribute__((ext_vector_type(4)))  float float4v;

#define BM 256
#define BN 256
#define BK 64     // 8 chunks of 8 halves (16 B) per row
#define NTHR 256  // 4 waves

#define VMCNT(n) asm volatile("s_waitcnt vmcnt(" #n ")" ::: "memory")

// Counted wait tied to staging chunks x,y (both matrices): the cvts chain
// through the asm (cannot hoist above the wait); volatile order vs the
// staging-load asms keeps the count exact. No sched wall (R9-verified).
#define VMWAIT_TIE8(n, x, y)                                                   \
    asm volatile("s_waitcnt vmcnt(" #n ")"                                     \
                 : "+v"(ra0[x]), "+v"(ra1[x]), "+v"(rb0[x]), "+v"(rb1[x]),     \
                   "+v"(ra0[y]), "+v"(ra1[y]), "+v"(rb0[y]), "+v"(rb1[y]))

// ---------------------------------------------------------------------------
// R11: geometry, not scheduling. R10's depth-2 pipeline had a register WAR
// race (ISSUE redefined staging regs before CVT consumed them) -> discarded;
// revert to the VERIFIED R9 schedule. R9's budget: 8400 cyc/CU/K-step vs
// LDS-pipe floor ~4000 (192 ds_read_b128 + 64 ds_write_b128 + conflicts) --
// LDS instructions are the binding resource and scheduling is exhausted
// (R4/R5/R9 all neutral). Cut the LDS work itself:
//   4 waves x (128x128 per wave) instead of 8 x (128x64):
//   per k-slice 4 A-frags + 4 B-frags feed 16 MFMAs = 0.5 reads/MFMA
//   (was 0.75); CU reads/step 192 -> 128; LDS floor ~4000 -> ~3000 cyc.
// Same 256^2 tile, BK=64, same XOR swizzle, same R9 K-step:
//   issue 32 staging loads -> SLICE0 -> tie vmcnt(24), cvt+write chunks 0,1
//   -> SLICE1 -> tie(16), cvt 2,3 -> SLICE2 -> tie(8), cvt 4,5 -> SLICE3
//   -> tie(0), cvt 6,7 -> __syncthreads.  One barrier per step; hazard
//   audit unchanged (reads buf[cur], writes buf[cur^1], separated by the
//   previous step's trailing barrier). Staging regs: use-before-redef (cvt
//   of tile t+1 happens in the SAME step as its loads' waits; next redef is
//   next step's ISSUE, after the barrier).
// Residency: 1 block/CU (128 KB LDS), 1 wave/SIMD. Unified VGPR/AGPR file:
// acc[4][4] (256 f32) -> AGPRs; staging 128 + frags 64 + addr ~40 VGPRs.
// All acc/reg indexing static (rule #20).
//
// quantize == fp32->f16 RNE cvt (reference e5m10 quantize incl. denormals)
// on stage for A/B, inline for bias.
// C[m][n] = sum_k qA[m][k]*qB[n][k] + q(bias[n]); mfma_f32_32x32x16_f16;
// XCD-aware block swizzle (2-wide bn strip per XCD, perf-only).
// ---------------------------------------------------------------------------
__global__ __launch_bounds__(256, 1)
void gemm_qf16_r11(const float* __restrict__ A, const float* __restrict__ B,
                   const float* __restrict__ bias, float* __restrict__ C,
                   int M, int N, int K) {
    __shared__ half_t sA[2][BM * BK];   // 2 x 32 KB
    __shared__ half_t sB[2][BN * BK];   // 2 x 32 KB

    const int t    = threadIdx.x;
    const int lane = t & 63;
    const int wave = t >> 6;            // 0..3
    const int wm   = (wave >> 1) * 128; // {0,128}
    const int wn   = (wave & 1) * 128;  // {0,128}

    // XCD-aware 1-D -> 2-D block swizzle (specialized for the 16x16 grid)
    const int nbx = N / BN, nby = M / BM;
    int bxi, byi;
    {
        const int b = blockIdx.x;
        if (nbx == 16 && nby == 16) {
            const int xcd = b & 7;      // round-robin assumption, perf-only
            const int s   = b >> 3;     // 0..31
            bxi = xcd * 2 + (s & 1);    // 2-wide bn strip per XCD
            byi = s >> 1;
        } else {
            bxi = b % nbx;
            byi = b / nbx;
        }
    }
    const int bm = byi * BM;
    const int bn = bxi * BN;

    // staging: 2048 16B-f16-chunks per matrix per K-step, 8 per thread;
    // chunk c = t + 256*s: row = c>>3, LDS pos = c&7, global k-chunk =
    // (c&7) ^ (row&7)  (inverse swizzle on the source address)
    const float* pa[8];
    const float* pb[8];
    int ldsoff[8];
    #pragma unroll
    for (int s = 0; s < 8; ++s) {
        const int c   = t + NTHR * s;
        const int row = c >> 3;
        const int kc  = (c & 7) ^ (row & 7);
        pa[s] = A + (long)(bm + row) * K + kc * 8;
        pb[s] = B + (long)(bn + row) * K + kc * 8;
        ldsoff[s] = c * 8;
    }

    f32x16 acc[4][4] = {};   // 256 f32 -> AGPRs (unified file); static idx only

    const int ml = lane & 31;   // m (or n) within 32-tile
    const int kg = lane >> 5;   // which 8-k half of the MFMA's K=16
    const int sw = ml & 7;      // row component of the XOR swizzle

    float4v ra0[8], ra1[8], rb0[8], rb1[8];   // 128 staging VGPRs

    const int NT = K / BK;      // 64 at K=4096

    // issue order: s ascending, per s: [A lo, A hi], [B lo, B hi]
    // -> group g (chunks 2g,2g+1) = loads 8g..8g+7; done at vmcnt 24/16/8/0
    #define ISSUE_LOADS()                                                      \
        do {                                                                   \
            _Pragma("unroll")                                                  \
            for (int s = 0; s < 8; ++s) {                                      \
                asm volatile("global_load_dwordx4 %0, %2, off\n\t"             \
                             "global_load_dwordx4 %1, %2, off offset:16"       \
                             : "=&v"(ra0[s]), "=&v"(ra1[s])                    \
                             : "v"(pa[s])                                      \
                             : "memory");                                      \
                asm volatile("global_load_dwordx4 %0, %2, off\n\t"             \
                             "global_load_dwordx4 %1, %2, off offset:16"       \
                             : "=&v"(rb0[s]), "=&v"(rb1[s])                    \
                             : "v"(pb[s])                                      \
                             : "memory");                                      \
                pa[s] += BK; pb[s] += BK;                                      \
            }                                                                  \
        } while (0)

    #define CVTWR1(g)                                                          \
        do {                                                                   \
            half8 ha, hb;                                                      \
            ha[0]=(half_t)ra0[g][0]; ha[1]=(half_t)ra0[g][1]; ha[2]=(half_t)ra0[g][2]; ha[3]=(half_t)ra0[g][3]; \
            ha[4]=(half_t)ra1[g][0]; ha[5]=(half_t)ra1[g][1]; ha[6]=(half_t)ra1[g][2]; ha[7]=(half_t)ra1[g][3]; \
            hb[0]=(half_t)rb0[g][0]; hb[1]=(half_t)rb0[g][1]; hb[2]=(half_t)rb0[g][2]; hb[3]=(half_t)rb0[g][3]; \
            hb[4]=(half_t)rb1[g][0]; hb[5]=(half_t)rb1[g][1]; hb[6]=(half_t)rb1[g][2]; hb[7]=(half_t)rb1[g][3]; \
            *(half8*)&sA[nxt][ldsoff[g]] = ha;                                 \
            *(half8*)&sB[nxt][ldsoff[g]] = hb;                                 \
        } while (0)

    #define SLICE(ks)                                                          \
        do {                                                                   \
            const int cp = 2 * (ks) + kg;                                      \
            half8 a_[4], b_[4];                                                \
            _Pragma("unroll")                                                  \
            for (int i = 0; i < 4; ++i)                                        \
                a_[i] = *(const half8*)&sA[cur][((wm + 32*i + ml) * 8 + (cp ^ sw)) * 8]; \
            _Pragma("unroll")                                                  \
            for (int j = 0; j < 4; ++j)                                        \
                b_[j] = *(const half8*)&sB[cur][((wn + 32*j + ml) * 8 + (cp ^ sw)) * 8]; \
            __builtin_amdgcn_s_setprio(1);                                     \
            _Pragma("unroll")                                                  \
            for (int i = 0; i < 4; ++i)                                        \
                _Pragma("unroll")                                              \
                for (int j = 0; j < 4; ++j)                                    \
                    acc[i][j] = __builtin_amdgcn_mfma_f32_32x32x16_f16(a_[i], b_[j], acc[i][j], 0, 0, 0); \
            __builtin_amdgcn_s_setprio(0);                                     \
        } while (0)

    // ---- prologue: synchronous load + cvt + write buf 0 ----
    #pragma unroll
    for (int s = 0; s < 8; ++s) {
        ra0[s] = *(const float4v*)(pa[s]);
        ra1[s] = *(const float4v*)(pa[s] + 4);
        rb0[s] = *(const float4v*)(pb[s]);
        rb1[s] = *(const float4v*)(pb[s] + 4);
        pa[s] += BK; pb[s] += BK;
    }
    {
        const int nxt = 0;
        CVTWR1(0); CVTWR1(1); CVTWR1(2); CVTWR1(3);
        CVTWR1(4); CVTWR1(5); CVTWR1(6); CVTWR1(7);
    }
    VMCNT(0);          // normalize the vm counter before counted waits
    __syncthreads();

    int cur = 0;
    for (int kt = 0; kt < NT - 1; ++kt) {
        const int nxt = cur ^ 1;

        ISSUE_LOADS();                 // tile kt+1: 32 loads in flight

        SLICE(0);
        VMWAIT_TIE8(24, 0, 1); CVTWR1(0); CVTWR1(1);
        SLICE(1);
        VMWAIT_TIE8(16, 2, 3); CVTWR1(2); CVTWR1(3);
        SLICE(2);
        VMWAIT_TIE8(8, 4, 5);  CVTWR1(4); CVTWR1(5);
        SLICE(3);
        VMWAIT_TIE8(0, 6, 7);  CVTWR1(6); CVTWR1(7);

        __syncthreads();
        cur ^= 1;
    }

    // ---- final tile: MFMA only ----
    SLICE(0); SLICE(1); SLICE(2); SLICE(3);

    // Epilogue. 32x32 C/D layout [m74/m101]: col = lane&31,
    // row = (reg&3) + 8*(reg>>2) + 4*(lane>>5)
    const int cl  = lane & 31;
    const int rbs = 4 * (lane >> 5);
    #pragma unroll
    for (int j = 0; j < 4; ++j) {
        const int col = bn + wn + j * 32 + cl;
        const float bq = (float)(half_t)bias[col];   // inline bias quantize
        #pragma unroll
        for (int i = 0; i < 4; ++i) {
            #pragma unroll
            for (int r = 0; r < 16; ++r) {
                const int row = bm + wm + i * 32 + (r & 3) + 8 * (r >> 2) + rbs;
                C[(long)row * N + col] = acc[i][j][r] + bq;
            }
        }
    }
    #undef SLICE
    #undef CVTWR1
    #undef ISSUE_LOADS
}

extern "C" void kernel_launch(void* const* d_in, const int* in_sizes, int n_in,
                              void* d_out, int out_size, void* d_ws, size_t ws_size,
                              hipStream_t stream) {
    const float* x    = (const float*)d_in[0];
    const float* w    = (const float*)d_in[1];
    const float* bias = (const float*)d_in[2];
    float* out = (float*)d_out;

    const int OUT = in_sizes[2];
    const int IN  = in_sizes[1] / OUT;
    const int M   = in_sizes[0] / IN;
    const int N   = OUT, K = IN;

    dim3 grid((N / BN) * (M / BM));
    gemm_qf16_r11<<<grid, NTHR, 0, stream>>>(x, w, bias, out, M, N, K);
    (void)d_ws; (void)ws_size; (void)n_in; (void)out_size;
}